// Round 3
// baseline (140.506 us; speedup 1.0000x reference)
//
#include <hip/hip_runtime.h>

// N_RNA=20000, N_PROT=5000, D=128, C=4, E=500000
#define DIM 128
#define NCLS 4

typedef _Float16 f16x4 __attribute__((ext_vector_type(4)));
typedef _Float16 f16x8 __attribute__((ext_vector_type(8)));
typedef float    f32x4 __attribute__((ext_vector_type(4)));

// ---------- merged fp32 -> fp16 conversion (both tables, one launch) ----------
__global__ __launch_bounds__(256) void cvt_both_kernel(
    const float* __restrict__ s1, _Float16* __restrict__ d1, int n1,
    const float* __restrict__ s2, _Float16* __restrict__ d2, int n2)
{
    // n1, n2 are multiples of 8, so an 8-group never straddles the boundary.
    const int total = n1 + n2;
    int i = (blockIdx.x * blockDim.x + threadIdx.x) * 8;
    const int stride = gridDim.x * blockDim.x * 8;
    for (; i < total; i += stride) {
        const float* s; _Float16* d; int j;
        if (i < n1) { s = s1; d = d1; j = i; }
        else        { s = s2; d = d2; j = i - n1; }
        const float4 a = *(const float4*)(s + j);
        const float4 b = *(const float4*)(s + j + 4);
        f16x8 o;
        o[0] = (_Float16)a.x; o[1] = (_Float16)a.y;
        o[2] = (_Float16)a.z; o[3] = (_Float16)a.w;
        o[4] = (_Float16)b.x; o[5] = (_Float16)b.y;
        o[6] = (_Float16)b.z; o[7] = (_Float16)b.w;
        *(f16x8*)(d + j) = o;
    }
}

// ---------- MFMA decoder (verified R1) ----------
// out[e, 0:4] = relu( (r[e] .* p[e]) @ WF ), WF[d, c] = sum_cc wrel[cc,d]*wcls[cc*4+c]
// One v_mfma_f32_16x16x32_f16 = 16 edges x 4 classes x K=32; 4 chained MFMAs = D=128.
//   A = WF^T (rows 0..3 = classes, 4..15 zero), B = q = r.*p (col = edge).
//   D layout col=lane&15, row=(lane>>4)*4+reg: lanes 0..15 hold float4 of classes.
// NOTE: launched TWICE this round as a timing probe — the kernel is idempotent
// (reads tables/indices only, writes out deterministically), so the second
// dispatch measures the warm-cache decoder duration in rocprof, and
// dur_us - 106.1 (R1 baseline) isolates T_decoder.
__global__ __launch_bounds__(256, 4) void decoder_mfma_kernel(
    const _Float16* __restrict__ rna,   // [N_RNA, D] f16
    const _Float16* __restrict__ prot,  // [N_PROT, D] f16
    const int*   __restrict__ ridx,
    const int*   __restrict__ pidx,
    const float* __restrict__ wrel,
    const float* __restrict__ wcls,
    float*       __restrict__ out,
    int nEdges)                          // requires nEdges % 32 == 0
{
    __shared__ _Float16 wf_lds[NCLS][DIM];
    {
        const int t = threadIdx.x;
        if (t < DIM) {
            const float w0 = wrel[0 * DIM + t];
            const float w1 = wrel[1 * DIM + t];
            const float w2 = wrel[2 * DIM + t];
            const float w3 = wrel[3 * DIM + t];
#pragma unroll
            for (int c = 0; c < NCLS; ++c) {
                wf_lds[c][t] = (_Float16)(w0 * wcls[0 * 4 + c] + w1 * wcls[1 * 4 + c] +
                                          w2 * wcls[2 * 4 + c] + w3 * wcls[3 * 4 + c]);
            }
        }
    }
    __syncthreads();

    const int lane = threadIdx.x & 63;
    const int l16  = lane & 15;   // edge-in-group (B cols) / class row (A)
    const int kg   = lane >> 4;   // k-subgroup 0..3 (8 f16 each)

    f16x8 awf[4];
    const f16x8 fzero = {};
#pragma unroll
    for (int f = 0; f < 4; ++f)
        awf[f] = (l16 < NCLS) ? *(const f16x8*)(&wf_lds[l16][f * 32 + kg * 8]) : fzero;

    const int wid   = (int)((blockIdx.x * blockDim.x + threadIdx.x) >> 6);
    const int nw    = (int)((gridDim.x * blockDim.x) >> 6);
    const int npair = nEdges >> 5;          // 32 edges per iteration

    const size_t khi  = (size_t)kg * 16;    // byte offset of k-subgroup in 256B row
    const char* rbase = (const char*)rna  + khi;
    const char* pbase = (const char*)prot + khi;

    int pr = wid;
    if (pr >= npair) return;
    int e0  = pr * 32;
    int riA = ridx[e0 + l16],      piA = pidx[e0 + l16];
    int riB = ridx[e0 + 16 + l16], piB = pidx[e0 + 16 + l16];

    for (;;) {
        // ---- issue all 16 gather dwordx4 loads back-to-back ----
        const char* ra = rbase + ((size_t)riA << 8);
        const char* pa = pbase + ((size_t)piA << 8);
        const char* rb = rbase + ((size_t)riB << 8);
        const char* pb = pbase + ((size_t)piB << 8);
        f16x8 rAv[4], pAv[4], rBv[4], pBv[4];
#pragma unroll
        for (int f = 0; f < 4; ++f) rAv[f] = *(const f16x8*)(ra + f * 64);
#pragma unroll
        for (int f = 0; f < 4; ++f) pAv[f] = *(const f16x8*)(pa + f * 64);
#pragma unroll
        for (int f = 0; f < 4; ++f) rBv[f] = *(const f16x8*)(rb + f * 64);
#pragma unroll
        for (int f = 0; f < 4; ++f) pBv[f] = *(const f16x8*)(pb + f * 64);

        // ---- prefetch next iteration's indices while gathers are in flight ----
        const int  prn  = pr + nw;
        const bool more = prn < npair;
        if (more) {
            const int en = prn * 32;
            riA = ridx[en + l16];      piA = pidx[en + l16];
            riB = ridx[en + 16 + l16]; piB = pidx[en + 16 + l16];
        }

        // ---- q = r .* p (packed f16), reduce via MFMA ----
        f32x4 accA = {}, accB = {};
#pragma unroll
        for (int f = 0; f < 4; ++f) {
            const f16x8 q = rAv[f] * pAv[f];
            accA = __builtin_amdgcn_mfma_f32_16x16x32_f16(awf[f], q, accA, 0, 0, 0);
        }
#pragma unroll
        for (int f = 0; f < 4; ++f) {
            const f16x8 q = rBv[f] * pBv[f];
            accB = __builtin_amdgcn_mfma_f32_16x16x32_f16(awf[f], q, accB, 0, 0, 0);
        }

        // ---- relu + contiguous float4 store (lanes 0..15 hold class rows) ----
        if (lane < 16) {
            f32x4 oA, oB;
#pragma unroll
            for (int j = 0; j < 4; ++j) {
                oA[j] = fmaxf(accA[j], 0.0f);
                oB[j] = fmaxf(accB[j], 0.0f);
            }
            *(f32x4*)(out + (size_t)(e0 + l16) * NCLS)      = oA;
            *(f32x4*)(out + (size_t)(e0 + 16 + l16) * NCLS) = oB;
        }

        if (!more) break;
        pr = prn;
        e0 = prn * 32;
    }
}

// ---------- fp32 fallback (handles any shape / tiny workspace) ----------
__device__ __forceinline__ float reduce4_f32(float b0, float b1, float b2, float b3, int lane)
{
    const bool lo1 = (lane & 1) == 0;
    float k0 = lo1 ? b0 : b2, s0 = lo1 ? b2 : b0;
    float k1 = lo1 ? b1 : b3, s1 = lo1 ? b3 : b1;
    float v0 = k0 + __shfl_xor(s0, 1, 32);
    float v1 = k1 + __shfl_xor(s1, 1, 32);
    const bool lo2 = (lane & 2) == 0;
    float k = lo2 ? v0 : v1, s = lo2 ? v1 : v0;
    float v = k + __shfl_xor(s, 2, 32);
    v += __shfl_xor(v, 4, 32);
    v += __shfl_xor(v, 8, 32);
    v += __shfl_xor(v, 16, 32);
    return v;
}

__global__ __launch_bounds__(256) void decoder_f32_kernel(
    const float* __restrict__ rna, const float* __restrict__ prot,
    const int* __restrict__ ridx, const int* __restrict__ pidx,
    const float* __restrict__ wrel, const float* __restrict__ wcls,
    float* __restrict__ out, int nEdges)
{
    const int lane32 = threadIdx.x & 31;
    const int hw     = (blockIdx.x * blockDim.x + threadIdx.x) >> 5;
    const int nhw    = (gridDim.x * blockDim.x) >> 5;
    const float4 w0 = *(const float4*)(wrel + 0 * DIM + lane32 * 4);
    const float4 w1 = *(const float4*)(wrel + 1 * DIM + lane32 * 4);
    const float4 w2 = *(const float4*)(wrel + 2 * DIM + lane32 * 4);
    const float4 w3 = *(const float4*)(wrel + 3 * DIM + lane32 * 4);
    float wc[16];
#pragma unroll
    for (int i = 0; i < 16; ++i) wc[i] = wcls[i];
    float4 wf[4];
#pragma unroll
    for (int j = 0; j < 4; ++j) {
        wf[j].x = wc[j] * w0.x + wc[4 + j] * w1.x + wc[8 + j] * w2.x + wc[12 + j] * w3.x;
        wf[j].y = wc[j] * w0.y + wc[4 + j] * w1.y + wc[8 + j] * w2.y + wc[12 + j] * w3.y;
        wf[j].z = wc[j] * w0.z + wc[4 + j] * w1.z + wc[8 + j] * w2.z + wc[12 + j] * w3.z;
        wf[j].w = wc[j] * w0.w + wc[4 + j] * w1.w + wc[8 + j] * w2.w + wc[12 + j] * w3.w;
    }
    const int cls   = ((lane32 & 1) << 1) | ((lane32 >> 1) & 1);
    const int lelem = lane32 * 4;
    for (int e = hw; e < nEdges; e += nhw) {
        const float4 r = *(const float4*)(rna  + (size_t)ridx[e] * DIM + lelem);
        const float4 p = *(const float4*)(prot + (size_t)pidx[e] * DIM + lelem);
        float qx = r.x * p.x, qy = r.y * p.y, qz = r.z * p.z, qw = r.w * p.w;
        float b0 = qx * wf[0].x + qy * wf[0].y + qz * wf[0].z + qw * wf[0].w;
        float b1 = qx * wf[1].x + qy * wf[1].y + qz * wf[1].z + qw * wf[1].w;
        float b2 = qx * wf[2].x + qy * wf[2].y + qz * wf[2].z + qw * wf[2].w;
        float b3 = qx * wf[3].x + qy * wf[3].y + qz * wf[3].z + qw * wf[3].w;
        const float v = reduce4_f32(b0, b1, b2, b3, lane32);
        if (lane32 < 4) out[(size_t)e * NCLS + cls] = fmaxf(v, 0.0f);
    }
}

extern "C" void kernel_launch(void* const* d_in, const int* in_sizes, int n_in,
                              void* d_out, int out_size, void* d_ws, size_t ws_size,
                              hipStream_t stream) {
    const float* rna  = (const float*)d_in[0];
    const float* prot = (const float*)d_in[1];
    const int*   ridx = (const int*)d_in[2];
    const int*   pidx = (const int*)d_in[3];
    const float* wrel = (const float*)d_in[4];
    const float* wcls = (const float*)d_in[5];
    float*       out  = (float*)d_out;

    const int nRnaElems  = in_sizes[0];   // 20000*128
    const int nProtElems = in_sizes[1];   // 5000*128
    const int nEdges     = in_sizes[2];   // 500000

    const size_t rnaBytes  = (size_t)nRnaElems * 2;
    const size_t needBytes = rnaBytes + (size_t)nProtElems * 2;

    if (ws_size >= needBytes && (nEdges % 32) == 0 && nEdges >= 32 &&
        (nRnaElems % 8) == 0 && (nProtElems % 8) == 0) {
        _Float16* rnaH  = (_Float16*)d_ws;
        _Float16* protH = (_Float16*)((char*)d_ws + rnaBytes);

        const int totalElems = nRnaElems + nProtElems;
        const int cvtBlocks  = (totalElems / 8 + 255) / 256;
        hipLaunchKernelGGL(cvt_both_kernel, dim3(cvtBlocks), dim3(256), 0, stream,
                           rna, rnaH, nRnaElems, prot, protH, nProtElems);

        // DIAGNOSTIC ROUND: launch the decoder twice (idempotent — identical
        // output both times). dur_us minus the R1 baseline (106.1) gives the
        // decoder's true duration; if >~35us each, the dispatches surface in
        // rocprof top-5 with their own FETCH_SIZE/MfmaUtil, resolving whether
        // the gather path is cache-resident or HBM/latency-bound.
        hipLaunchKernelGGL(decoder_mfma_kernel, dim3(1024), dim3(256), 0, stream,
                           rnaH, protH, ridx, pidx, wrel, wcls, out, nEdges);
        hipLaunchKernelGGL(decoder_mfma_kernel, dim3(1024), dim3(256), 0, stream,
                           rnaH, protH, ridx, pidx, wrel, wcls, out, nEdges);
    } else {
        hipLaunchKernelGGL(decoder_f32_kernel, dim3(8192), dim3(256), 0, stream,
                           rna, prot, ridx, pidx, wrel, wcls, out, nEdges);
    }
}

// Round 4
// 104.040 us; speedup vs baseline: 1.3505x; 1.3505x over previous
//
#include <hip/hip_runtime.h>

// N_RNA=20000, N_PROT=5000, D=128, C=4, E=500000
#define DIM 128
#define NCLS 4
#define ITER 4   // 32-edge units per wave (static)

typedef _Float16 f16x8 __attribute__((ext_vector_type(8)));
typedef float    f32x4 __attribute__((ext_vector_type(4)));

// ---------- merged fp32 -> fp16 conversion (both tables, one launch) ----------
__global__ __launch_bounds__(256) void cvt_both_kernel(
    const float* __restrict__ s1, _Float16* __restrict__ d1, int n1,
    const float* __restrict__ s2, _Float16* __restrict__ d2, int n2)
{
    // n1, n2 are multiples of 8, so an 8-group never straddles the boundary.
    const int total = n1 + n2;
    int i = (blockIdx.x * blockDim.x + threadIdx.x) * 8;
    const int stride = gridDim.x * blockDim.x * 8;
    for (; i < total; i += stride) {
        const float* s; _Float16* d; int j;
        if (i < n1) { s = s1; d = d1; j = i; }
        else        { s = s2; d = d2; j = i - n1; }
        const float4 a = *(const float4*)(s + j);
        const float4 b = *(const float4*)(s + j + 4);
        f16x8 o;
        o[0] = (_Float16)a.x; o[1] = (_Float16)a.y;
        o[2] = (_Float16)a.z; o[3] = (_Float16)a.w;
        o[4] = (_Float16)b.x; o[5] = (_Float16)b.y;
        o[6] = (_Float16)b.z; o[7] = (_Float16)b.w;
        *(f16x8*)(d + j) = o;
    }
}

// ---------- two-phase D-split MFMA decoder ----------
// out[e,0:4] = relu( (r[e].*p[e]) @ WF ), WF[d,c] = sum_cc wrel[cc,d]*wcls[cc*4+c].
// Phase h processes d in [h*64, h*64+64) for ALL of this wave's edges before
// phase h+1 — so the globally-live table footprint per phase is
// RNA-half (2.56MB) + prot-half (0.64MB) = 3.2MB < 4MB per-XCD L2
// (full f16 tables are 6.4MB > 4MB -> thrash; R3 decoder FETCH_SIZE was ~7x
// the table set). __syncthreads() between phases keeps a block's waves
// phase-aligned and stops the compiler hoisting phase-1 loads.
// Accumulator chain applies awf[0],awf[1] (h=0) then awf[2],awf[3] (h=1) —
// identical order to the verified R1 kernel -> bitwise-identical output.
// MFMA mapping (16x16x32, C/D col=lane&15, row=(lane>>4)*4+reg):
//   A = WF^T (rows 0..3 classes, 4..15 zero), B = q = r.*p (col = edge),
//   lane (l16,kg) holds k = f*32 + kg*8 .. +7 for fragment f.
__global__ __launch_bounds__(256, 3) void decoder_phase_kernel(
    const _Float16* __restrict__ rna,   // [N_RNA, D] f16
    const _Float16* __restrict__ prot,  // [N_PROT, D] f16
    const int*   __restrict__ ridx,
    const int*   __restrict__ pidx,
    const float* __restrict__ wrel,
    const float* __restrict__ wcls,
    float*       __restrict__ out,
    int nEdges)                          // requires nEdges % 32 == 0
{
    __shared__ _Float16 wf_lds[NCLS][DIM];
    {
        const int t = threadIdx.x;
        if (t < DIM) {
            const float w0 = wrel[0 * DIM + t];
            const float w1 = wrel[1 * DIM + t];
            const float w2 = wrel[2 * DIM + t];
            const float w3 = wrel[3 * DIM + t];
#pragma unroll
            for (int c = 0; c < NCLS; ++c) {
                wf_lds[c][t] = (_Float16)(w0 * wcls[0 * 4 + c] + w1 * wcls[1 * 4 + c] +
                                          w2 * wcls[2 * 4 + c] + w3 * wcls[3 * 4 + c]);
            }
        }
    }
    __syncthreads();

    const int lane = threadIdx.x & 63;
    const int l16  = lane & 15;   // edge-in-group (B cols) / class row (A)
    const int kg   = lane >> 4;   // k-subgroup 0..3 (8 f16 each)

    f16x8 awf[4];
    const f16x8 fzero = {};
#pragma unroll
    for (int f = 0; f < 4; ++f)
        awf[f] = (l16 < NCLS) ? *(const f16x8*)(&wf_lds[l16][f * 32 + kg * 8]) : fzero;

    const int wid = (int)((blockIdx.x * blockDim.x + threadIdx.x) >> 6);
    const int nU  = nEdges >> 5;          // 32-edge units
    const int u0  = wid * ITER;
    // NOTE: no early return — later __syncthreads() must see all waves.
    // Out-of-range units use row 0 (valid memory) and skip their stores.

    int riA[ITER], piA[ITER], riB[ITER], piB[ITER];
    bool vld[ITER];
#pragma unroll
    for (int u = 0; u < ITER; ++u) {
        const int un = u0 + u;
        vld[u] = un < nU;
        const int e = vld[u] ? (un << 5) : 0;
        riA[u] = ridx[e + l16];      piA[u] = pidx[e + l16];
        riB[u] = ridx[e + 16 + l16]; piB[u] = pidx[e + 16 + l16];
    }

    f32x4 accA[ITER], accB[ITER];
#pragma unroll
    for (int u = 0; u < ITER; ++u) { accA[u] = (f32x4){}; accB[u] = (f32x4){}; }

    // depth-2 pipeline buffers; slots indexed by compile-time (u&1) only (rule #20)
    f16x8 bRA0[2], bRA1[2], bPA0[2], bPA1[2];
    f16x8 bRB0[2], bRB1[2], bPB0[2], bPB1[2];

#pragma unroll
    for (int h = 0; h < 2; ++h) {
        const char* rb = (const char*)rna  + h * 128 + kg * 16;
        const char* pb = (const char*)prot + h * 128 + kg * 16;

#define LOADU(u, s) do {                                                     \
        const char* ra_ = rb + ((size_t)riA[u] << 8);                        \
        const char* pa_ = pb + ((size_t)piA[u] << 8);                        \
        const char* rc_ = rb + ((size_t)riB[u] << 8);                        \
        const char* pc_ = pb + ((size_t)piB[u] << 8);                        \
        bRA0[s] = *(const f16x8*)(ra_); bRA1[s] = *(const f16x8*)(ra_ + 64); \
        bPA0[s] = *(const f16x8*)(pa_); bPA1[s] = *(const f16x8*)(pa_ + 64); \
        bRB0[s] = *(const f16x8*)(rc_); bRB1[s] = *(const f16x8*)(rc_ + 64); \
        bPB0[s] = *(const f16x8*)(pc_); bPB1[s] = *(const f16x8*)(pc_ + 64); \
    } while (0)

        LOADU(0, 0);
#pragma unroll
        for (int u = 0; u < ITER; ++u) {
            const int s = u & 1;
            if (u + 1 < ITER) LOADU(u + 1, (u + 1) & 1);
            const f16x8 qa0 = bRA0[s] * bPA0[s];
            accA[u] = __builtin_amdgcn_mfma_f32_16x16x32_f16(awf[2 * h + 0], qa0, accA[u], 0, 0, 0);
            const f16x8 qa1 = bRA1[s] * bPA1[s];
            accA[u] = __builtin_amdgcn_mfma_f32_16x16x32_f16(awf[2 * h + 1], qa1, accA[u], 0, 0, 0);
            const f16x8 qb0 = bRB0[s] * bPB0[s];
            accB[u] = __builtin_amdgcn_mfma_f32_16x16x32_f16(awf[2 * h + 0], qb0, accB[u], 0, 0, 0);
            const f16x8 qb1 = bRB1[s] * bPB1[s];
            accB[u] = __builtin_amdgcn_mfma_f32_16x16x32_f16(awf[2 * h + 1], qb1, accB[u], 0, 0, 0);
        }
#undef LOADU

        if (h == 0) __syncthreads();   // phase fence: drains loads, aligns waves
    }

    // ---- relu + contiguous float4 stores (lanes 0..15 hold the class rows) ----
    if (lane < 16) {
#pragma unroll
        for (int u = 0; u < ITER; ++u) {
            if (!vld[u]) continue;
            const int e0 = (u0 + u) << 5;
            f32x4 oA, oB;
#pragma unroll
            for (int j = 0; j < 4; ++j) {
                oA[j] = fmaxf(accA[u][j], 0.0f);
                oB[j] = fmaxf(accB[u][j], 0.0f);
            }
            *(f32x4*)(out + (size_t)(e0 + l16) * NCLS)      = oA;
            *(f32x4*)(out + (size_t)(e0 + 16 + l16) * NCLS) = oB;
        }
    }
}

// ---------- fp32 fallback (handles any shape / tiny workspace) ----------
__device__ __forceinline__ float reduce4_f32(float b0, float b1, float b2, float b3, int lane)
{
    const bool lo1 = (lane & 1) == 0;
    float k0 = lo1 ? b0 : b2, s0 = lo1 ? b2 : b0;
    float k1 = lo1 ? b1 : b3, s1 = lo1 ? b3 : b1;
    float v0 = k0 + __shfl_xor(s0, 1, 32);
    float v1 = k1 + __shfl_xor(s1, 1, 32);
    const bool lo2 = (lane & 2) == 0;
    float k = lo2 ? v0 : v1, s = lo2 ? v1 : v0;
    float v = k + __shfl_xor(s, 2, 32);
    v += __shfl_xor(v, 4, 32);
    v += __shfl_xor(v, 8, 32);
    v += __shfl_xor(v, 16, 32);
    return v;
}

__global__ __launch_bounds__(256) void decoder_f32_kernel(
    const float* __restrict__ rna, const float* __restrict__ prot,
    const int* __restrict__ ridx, const int* __restrict__ pidx,
    const float* __restrict__ wrel, const float* __restrict__ wcls,
    float* __restrict__ out, int nEdges)
{
    const int lane32 = threadIdx.x & 31;
    const int hw     = (blockIdx.x * blockDim.x + threadIdx.x) >> 5;
    const int nhw    = (gridDim.x * blockDim.x) >> 5;
    const float4 w0 = *(const float4*)(wrel + 0 * DIM + lane32 * 4);
    const float4 w1 = *(const float4*)(wrel + 1 * DIM + lane32 * 4);
    const float4 w2 = *(const float4*)(wrel + 2 * DIM + lane32 * 4);
    const float4 w3 = *(const float4*)(wrel + 3 * DIM + lane32 * 4);
    float wc[16];
#pragma unroll
    for (int i = 0; i < 16; ++i) wc[i] = wcls[i];
    float4 wf[4];
#pragma unroll
    for (int j = 0; j < 4; ++j) {
        wf[j].x = wc[j] * w0.x + wc[4 + j] * w1.x + wc[8 + j] * w2.x + wc[12 + j] * w3.x;
        wf[j].y = wc[j] * w0.y + wc[4 + j] * w1.y + wc[8 + j] * w2.y + wc[12 + j] * w3.y;
        wf[j].z = wc[j] * w0.z + wc[4 + j] * w1.z + wc[8 + j] * w2.z + wc[12 + j] * w3.z;
        wf[j].w = wc[j] * w0.w + wc[4 + j] * w1.w + wc[8 + j] * w2.w + wc[12 + j] * w3.w;
    }
    const int cls   = ((lane32 & 1) << 1) | ((lane32 >> 1) & 1);
    const int lelem = lane32 * 4;
    for (int e = hw; e < nEdges; e += nhw) {
        const float4 r = *(const float4*)(rna  + (size_t)ridx[e] * DIM + lelem);
        const float4 p = *(const float4*)(prot + (size_t)pidx[e] * DIM + lelem);
        float qx = r.x * p.x, qy = r.y * p.y, qz = r.z * p.z, qw = r.w * p.w;
        float b0 = qx * wf[0].x + qy * wf[0].y + qz * wf[0].z + qw * wf[0].w;
        float b1 = qx * wf[1].x + qy * wf[1].y + qz * wf[1].z + qw * wf[1].w;
        float b2 = qx * wf[2].x + qy * wf[2].y + qz * wf[2].z + qw * wf[2].w;
        float b3 = qx * wf[3].x + qy * wf[3].y + qz * wf[3].z + qw * wf[3].w;
        const float v = reduce4_f32(b0, b1, b2, b3, lane32);
        if (lane32 < 4) out[(size_t)e * NCLS + cls] = fmaxf(v, 0.0f);
    }
}

extern "C" void kernel_launch(void* const* d_in, const int* in_sizes, int n_in,
                              void* d_out, int out_size, void* d_ws, size_t ws_size,
                              hipStream_t stream) {
    const float* rna  = (const float*)d_in[0];
    const float* prot = (const float*)d_in[1];
    const int*   ridx = (const int*)d_in[2];
    const int*   pidx = (const int*)d_in[3];
    const float* wrel = (const float*)d_in[4];
    const float* wcls = (const float*)d_in[5];
    float*       out  = (float*)d_out;

    const int nRnaElems  = in_sizes[0];   // 20000*128
    const int nProtElems = in_sizes[1];   // 5000*128
    const int nEdges     = in_sizes[2];   // 500000

    const size_t rnaBytes  = (size_t)nRnaElems * 2;
    const size_t needBytes = rnaBytes + (size_t)nProtElems * 2;

    if (ws_size >= needBytes && (nEdges % 32) == 0 && nEdges >= 32 &&
        (nRnaElems % 8) == 0 && (nProtElems % 8) == 0) {
        _Float16* rnaH  = (_Float16*)d_ws;
        _Float16* protH = (_Float16*)((char*)d_ws + rnaBytes);

        const int totalElems = nRnaElems + nProtElems;
        const int cvtBlocks  = (totalElems / 8 + 255) / 256;
        hipLaunchKernelGGL(cvt_both_kernel, dim3(cvtBlocks), dim3(256), 0, stream,
                           rna, rnaH, nRnaElems, prot, protH, nProtElems);

        // One wave per ITER(=4) 32-edge units; 4 waves/block -> 16 units/block.
        const int nU     = nEdges >> 5;
        const int blocks = (nU + ITER * 4 - 1) / (ITER * 4);   // 977 for E=500000
        hipLaunchKernelGGL(decoder_phase_kernel, dim3(blocks), dim3(256), 0, stream,
                           rnaH, protH, ridx, pidx, wrel, wcls, out, nEdges);
    } else {
        hipLaunchKernelGGL(decoder_f32_kernel, dim3(8192), dim3(256), 0, stream,
                           rna, prot, ridx, pidx, wrel, wcls, out, nEdges);
    }
}

// Round 5
// 91.271 us; speedup vs baseline: 1.5394x; 1.1399x over previous
//
#include <hip/hip_runtime.h>

// N_RNA=20000, N_PROT=5000, D=128, C=4, E=500000
#define DIM 128
#define NCLS 4
#define UNIT 16   // edges per unit = one 16-col MFMA group
#define ITER 8    // units per wave

typedef _Float16 f16x8 __attribute__((ext_vector_type(8)));
typedef float    f32x4 __attribute__((ext_vector_type(4)));

// ---------- merged fp32 -> fp16 conversion (both tables, one launch) ----------
__global__ __launch_bounds__(256) void cvt_both_kernel(
    const float* __restrict__ s1, _Float16* __restrict__ d1, int n1,
    const float* __restrict__ s2, _Float16* __restrict__ d2, int n2)
{
    const int total = n1 + n2;
    int i = (blockIdx.x * blockDim.x + threadIdx.x) * 8;
    const int stride = gridDim.x * blockDim.x * 8;
    for (; i < total; i += stride) {
        const float* s; _Float16* d; int j;
        if (i < n1) { s = s1; d = d1; j = i; }
        else        { s = s2; d = d2; j = i - n1; }
        const float4 a = *(const float4*)(s + j);
        const float4 b = *(const float4*)(s + j + 4);
        f16x8 o;
        o[0] = (_Float16)a.x; o[1] = (_Float16)a.y;
        o[2] = (_Float16)a.z; o[3] = (_Float16)a.w;
        o[4] = (_Float16)b.x; o[5] = (_Float16)b.y;
        o[6] = (_Float16)b.z; o[7] = (_Float16)b.w;
        *(f16x8*)(d + j) = o;
    }
}

// ---------- coalesced-gather LDS-transpose MFMA decoder ----------
// Theory: R0-R4 showed the decoder is TA-transaction bound: fragment-layout
// gathers touch 16 cache lines per instruction (16 rows x 64B). Here each
// dwordx4 instruction loads 4 FULL 256B rows (16 lanes/row, contiguous) =
// 8 fully-used 128B transactions — 2x fewer. The lane->fragment transpose
// goes through a per-wave 8KB LDS slice (wave-private, no __syncthreads;
// DS ops within a wave execute in order).
//   Stage write (op,i): lane(h=lane>>4,sl=lane&15): row = op*16 + 4h + i,
//     global = tbl[idx[e0+4h+i]] + sl*16 (coalesced), LDS slot = sl ^ (4h+i).
//   Frag read: lane(l16,kg), f: row l16 (RNA) / 16+l16 (prot),
//     slot t = (4f+kg) ^ l16  -> bytes f*64+kg*16 of the row = k-slice f*32+kg*8.
//   XOR swizzle is bank-uniform both directions (8 lanes per 4-bank group).
// Fragment values and MFMA order identical to the verified R1 kernel ->
// bitwise-identical output. D layout: lanes 0..15 hold float4 of classes.
__global__ __launch_bounds__(256, 4) void decoder_lds_kernel(
    const _Float16* __restrict__ rna,   // [N_RNA, D] f16
    const _Float16* __restrict__ prot,  // [N_PROT, D] f16
    const int*   __restrict__ ridx,
    const int*   __restrict__ pidx,
    const float* __restrict__ wrel,
    const float* __restrict__ wcls,
    float*       __restrict__ out,
    int nEdges)                          // requires nEdges % 32 == 0
{
    __shared__ _Float16 wf_lds[NCLS][DIM];
    __shared__ __align__(16) char stage[4][2 * UNIT * 256];   // 4 waves x 8KB
    {
        const int t = threadIdx.x;
        if (t < DIM) {
            const float w0 = wrel[0 * DIM + t];
            const float w1 = wrel[1 * DIM + t];
            const float w2 = wrel[2 * DIM + t];
            const float w3 = wrel[3 * DIM + t];
#pragma unroll
            for (int c = 0; c < NCLS; ++c) {
                wf_lds[c][t] = (_Float16)(w0 * wcls[0 * 4 + c] + w1 * wcls[1 * 4 + c] +
                                          w2 * wcls[2 * 4 + c] + w3 * wcls[3 * 4 + c]);
            }
        }
    }
    __syncthreads();

    const int lane = threadIdx.x & 63;
    const int l16  = lane & 15;   // edge-in-group (B cols) / class row (A)
    const int kg   = lane >> 4;   // k-subgroup 0..3 (8 f16 each)

    f16x8 awf[4];
    const f16x8 fz = {};
#pragma unroll
    for (int f = 0; f < 4; ++f)
        awf[f] = (l16 < NCLS) ? *(const f16x8*)(&wf_lds[l16][f * 32 + kg * 8]) : fz;

    char* slice = stage[threadIdx.x >> 6];

    const int wid = blockIdx.x * 4 + (threadIdx.x >> 6);
    const int nU  = nEdges >> 4;          // 16-edge units
    const int u0  = wid * ITER;

    const int h4   = (lane >> 4) << 2;    // row-group base 4*(lane/16)
    const int sl16 = (lane & 15) << 4;    // byte-in-row for coalesced stage load

    const char* rna8  = (const char*)rna;
    const char* prot8 = (const char*)prot;

    bool vu[ITER];
    int  eu[ITER];
#pragma unroll
    for (int u = 0; u < ITER; ++u) {
        const int un = u0 + u;
        vu[u] = un < nU;
        eu[u] = vu[u] ? (un << 4) : 0;    // invalid units read row-0 area, skip store
    }

    int4  riv[2], piv[2];                 // idx slots (compile-time indexed)
    f16x8 stg[2][8];                      // depth-2 staging regs

#define LOADIDX(u_, s_) do {                                     \
        riv[s_] = *(const int4*)(ridx + eu[u_] + h4);            \
        piv[s_] = *(const int4*)(pidx + eu[u_] + h4); } while (0)

#define GLOB1(s_, op_, i_, idx_)                                                 \
        stg[s_][(op_) * 4 + (i_)] =                                              \
            *(const f16x8*)(((op_) ? prot8 : rna8) + ((size_t)(idx_) << 8) + sl16)

#define GLOB(s_) do {                                            \
        GLOB1(s_, 0, 0, riv[s_].x); GLOB1(s_, 0, 1, riv[s_].y);  \
        GLOB1(s_, 0, 2, riv[s_].z); GLOB1(s_, 0, 3, riv[s_].w);  \
        GLOB1(s_, 1, 0, piv[s_].x); GLOB1(s_, 1, 1, piv[s_].y);  \
        GLOB1(s_, 1, 2, piv[s_].z); GLOB1(s_, 1, 3, piv[s_].w); } while (0)

#define DSW1(s_, op_, i_)                                                        \
        *(f16x8*)(slice + ((op_) * 16 + h4 + (i_)) * 256 +                       \
                  (((lane & 15) ^ (h4 + (i_))) << 4)) = stg[s_][(op_) * 4 + (i_)]

#define DSW(s_) do {                                             \
        DSW1(s_, 0, 0); DSW1(s_, 0, 1); DSW1(s_, 0, 2); DSW1(s_, 0, 3); \
        DSW1(s_, 1, 0); DSW1(s_, 1, 1); DSW1(s_, 1, 2); DSW1(s_, 1, 3); } while (0)

    // prologue: idx(0) -> glob(0) in flight; idx(1) in flight
    LOADIDX(0, 0);
    GLOB(0);
    LOADIDX(1, 1);

#pragma unroll
    for (int u = 0; u < ITER; ++u) {
        const int s  = u & 1;
        const int ns = s ^ 1;
        if (u + 1 < ITER) GLOB(ns);           // issue next unit's row loads
        if (u + 2 < ITER) LOADIDX(u + 2, s);  // idx two units ahead

        DSW(s);   // vmcnt-waits glob(u) only; glob(u+1) stays in flight

        f32x4 acc = {};
#pragma unroll
        for (int f = 0; f < 4; ++f) {
            const int t = ((f << 2) | kg) ^ l16;
            const f16x8 rv = *(const f16x8*)(slice + l16 * 256 + (t << 4));
            const f16x8 pv = *(const f16x8*)(slice + (16 + l16) * 256 + (t << 4));
            const f16x8 q  = rv * pv;
            acc = __builtin_amdgcn_mfma_f32_16x16x32_f16(awf[f], q, acc, 0, 0, 0);
        }

        if (lane < 16 && vu[u]) {
            f32x4 o;
#pragma unroll
            for (int j = 0; j < 4; ++j) o[j] = fmaxf(acc[j], 0.0f);
            *(f32x4*)(out + (size_t)(eu[u] + l16) * NCLS) = o;
        }
    }
#undef LOADIDX
#undef GLOB1
#undef GLOB
#undef DSW1
#undef DSW
}

// ---------- fp32 fallback (handles any shape / tiny workspace) ----------
__device__ __forceinline__ float reduce4_f32(float b0, float b1, float b2, float b3, int lane)
{
    const bool lo1 = (lane & 1) == 0;
    float k0 = lo1 ? b0 : b2, s0 = lo1 ? b2 : b0;
    float k1 = lo1 ? b1 : b3, s1 = lo1 ? b3 : b1;
    float v0 = k0 + __shfl_xor(s0, 1, 32);
    float v1 = k1 + __shfl_xor(s1, 1, 32);
    const bool lo2 = (lane & 2) == 0;
    float k = lo2 ? v0 : v1, s = lo2 ? v1 : v0;
    float v = k + __shfl_xor(s, 2, 32);
    v += __shfl_xor(v, 4, 32);
    v += __shfl_xor(v, 8, 32);
    v += __shfl_xor(v, 16, 32);
    return v;
}

__global__ __launch_bounds__(256) void decoder_f32_kernel(
    const float* __restrict__ rna, const float* __restrict__ prot,
    const int* __restrict__ ridx, const int* __restrict__ pidx,
    const float* __restrict__ wrel, const float* __restrict__ wcls,
    float* __restrict__ out, int nEdges)
{
    const int lane32 = threadIdx.x & 31;
    const int hw     = (blockIdx.x * blockDim.x + threadIdx.x) >> 5;
    const int nhw    = (gridDim.x * blockDim.x) >> 5;
    const float4 w0 = *(const float4*)(wrel + 0 * DIM + lane32 * 4);
    const float4 w1 = *(const float4*)(wrel + 1 * DIM + lane32 * 4);
    const float4 w2 = *(const float4*)(wrel + 2 * DIM + lane32 * 4);
    const float4 w3 = *(const float4*)(wrel + 3 * DIM + lane32 * 4);
    float wc[16];
#pragma unroll
    for (int i = 0; i < 16; ++i) wc[i] = wcls[i];
    float4 wf[4];
#pragma unroll
    for (int j = 0; j < 4; ++j) {
        wf[j].x = wc[j] * w0.x + wc[4 + j] * w1.x + wc[8 + j] * w2.x + wc[12 + j] * w3.x;
        wf[j].y = wc[j] * w0.y + wc[4 + j] * w1.y + wc[8 + j] * w2.y + wc[12 + j] * w3.y;
        wf[j].z = wc[j] * w0.z + wc[4 + j] * w1.z + wc[8 + j] * w2.z + wc[12 + j] * w3.z;
        wf[j].w = wc[j] * w0.w + wc[4 + j] * w1.w + wc[8 + j] * w2.w + wc[12 + j] * w3.w;
    }
    const int cls   = ((lane32 & 1) << 1) | ((lane32 >> 1) & 1);
    const int lelem = lane32 * 4;
    for (int e = hw; e < nEdges; e += nhw) {
        const float4 r = *(const float4*)(rna  + (size_t)ridx[e] * DIM + lelem);
        const float4 p = *(const float4*)(prot + (size_t)pidx[e] * DIM + lelem);
        float qx = r.x * p.x, qy = r.y * p.y, qz = r.z * p.z, qw = r.w * p.w;
        float b0 = qx * wf[0].x + qy * wf[0].y + qz * wf[0].z + qw * wf[0].w;
        float b1 = qx * wf[1].x + qy * wf[1].y + qz * wf[1].z + qw * wf[1].w;
        float b2 = qx * wf[2].x + qy * wf[2].y + qz * wf[2].z + qw * wf[2].w;
        float b3 = qx * wf[3].x + qy * wf[3].y + qz * wf[3].z + qw * wf[3].w;
        const float v = reduce4_f32(b0, b1, b2, b3, lane32);
        if (lane32 < 4) out[(size_t)e * NCLS + cls] = fmaxf(v, 0.0f);
    }
}

extern "C" void kernel_launch(void* const* d_in, const int* in_sizes, int n_in,
                              void* d_out, int out_size, void* d_ws, size_t ws_size,
                              hipStream_t stream) {
    const float* rna  = (const float*)d_in[0];
    const float* prot = (const float*)d_in[1];
    const int*   ridx = (const int*)d_in[2];
    const int*   pidx = (const int*)d_in[3];
    const float* wrel = (const float*)d_in[4];
    const float* wcls = (const float*)d_in[5];
    float*       out  = (float*)d_out;

    const int nRnaElems  = in_sizes[0];   // 20000*128
    const int nProtElems = in_sizes[1];   // 5000*128
    const int nEdges     = in_sizes[2];   // 500000

    const size_t rnaBytes  = (size_t)nRnaElems * 2;
    const size_t needBytes = rnaBytes + (size_t)nProtElems * 2;

    if (ws_size >= needBytes && (nEdges % 32) == 0 && nEdges >= 32 &&
        (nRnaElems % 8) == 0 && (nProtElems % 8) == 0) {
        _Float16* rnaH  = (_Float16*)d_ws;
        _Float16* protH = (_Float16*)((char*)d_ws + rnaBytes);

        const int totalElems = nRnaElems + nProtElems;
        const int cvtBlocks  = (totalElems / 8 + 255) / 256;
        hipLaunchKernelGGL(cvt_both_kernel, dim3(cvtBlocks), dim3(256), 0, stream,
                           rna, rnaH, nRnaElems, prot, protH, nProtElems);

        // 16-edge units, 8 units/wave, 4 waves/block.
        // E=500000 -> 31250 units -> 3907 waves -> 977 blocks; at
        // __launch_bounds__(256,4) + 33KB LDS/block = 4 blocks/CU -> 1024
        // resident: the whole grid is co-resident (no tail round).
        const int nU     = nEdges >> 4;
        const int waves  = (nU + ITER - 1) / ITER;
        const int blocks = (waves + 3) / 4;
        hipLaunchKernelGGL(decoder_lds_kernel, dim3(blocks), dim3(256), 0, stream,
                           rnaH, protH, ridx, pidx, wrel, wcls, out, nEdges);
    } else {
        hipLaunchKernelGGL(decoder_f32_kernel, dim3(8192), dim3(256), 0, stream,
                           rna, prot, ridx, pidx, wrel, wcls, out, nEdges);
    }
}